// Round 6
// baseline (392.869 us; speedup 1.0000x reference)
//
#include <hip/hip_runtime.h>
#include <hip/hip_bf16.h>
#include <stdint.h>

#define HID 256
#define BM  64
#define LDA 68    // lp_mono As row stride (34 dwords == 2 mod 32: measured zero-conflict)
#define LDC 264   // Cs row stride in ushorts (132 dwords)

typedef __bf16 bf16x8 __attribute__((ext_vector_type(8)));
typedef float  f32x4  __attribute__((ext_vector_type(4)));

__device__ __forceinline__ ushort f2bf(float x) {
    union { float f; uint32_t u; } v; v.f = x;
    uint32_t u = v.u;
    uint32_t r = u + 0x7fffu + ((u >> 16) & 1u);   // RNE
    return (ushort)(r >> 16);
}

__device__ __forceinline__ uint32_t pack2bf(float a, float b) {
    union { float f; uint32_t u; } ua, ub;
    ua.f = a; ub.f = b;
    return __builtin_amdgcn_perm(ub.u + 0x8000u, ua.u + 0x8000u, 0x07060302u);
}

__device__ __forceinline__ float uaf(uint32_t x) {
    union { uint32_t u; float f; } c; c.u = x; return c.f;
}

// W1[512][256] fp32 -> Wt4 bf16, layout [(c*2+ks)*4+q][n 0..255][j 0..7]
// where global k = c*64 + ks*32 + q*8 + j. B-fragment loads in node_gemm are then
// 16B-contiguous per lane, 256B-contiguous per quad.
__global__ void conv_w1(const float* __restrict__ W1, ushort* __restrict__ Wt4) {
    __shared__ ushort tr[32][33];
    const int bk = blockIdx.x >> 3;   // k-tile 0..15
    const int bn = blockIdx.x & 7;    // n-tile 0..7
    const int t  = threadIdx.x;
    #pragma unroll
    for (int i = 0; i < 4; ++i) {
        int e = t + 256 * i; int r = e >> 5, cc = e & 31;
        tr[cc][r] = f2bf(W1[(size_t)(bk * 32 + r) * HID + bn * 32 + cc]);
    }
    __syncthreads();
    #pragma unroll
    for (int i = 0; i < 4; ++i) {
        int e = t + 256 * i; int rn = e >> 5, ck = e & 31;
        int k = bk * 32 + ck;
        int grp = k >> 3;               // (c*2+ks)*4+q  == k/8
        int j   = k & 7;
        int n   = bn * 32 + rn;
        Wt4[((size_t)grp * HID + n) * 8 + j] = tr[rn][ck];
    }
}

// -------- phase 1: dense per-node GEMM  u = emb @ W1half  (bf16 out) --------
// No LDS staging, no in-loop barriers: per interval, B loads issue first, then A
// loads, so the compiler's vmcnt wait for B leaves A in flight. TLP across the
// 12 resident waves hides the rest.
__global__ __launch_bounds__(256, 3)
void node_gemm(const float* __restrict__ emb0, const float* __restrict__ emb1,
               const ushort* __restrict__ Wt4,
               ushort* __restrict__ u0, ushort* __restrict__ u1,
               int n0, int n1, int nb0) {
    __shared__ ushort Cs[BM * LDC];   // 33792 B (epilogue only)

    const int t    = threadIdx.x;
    const int tb   = (blockIdx.x >= nb0) ? 1 : 0;
    const int bloc = blockIdx.x - tb * nb0;
    const float*  emb = tb ? emb1 : emb0;
    ushort*       uo  = tb ? u1 : u0;
    const int     n   = tb ? n1 : n0;
    const int     e0  = bloc * BM;

    const int wave = t >> 6, lane = t & 63, q = lane >> 4, cl = lane & 15;

    const float* arow[4];
    #pragma unroll
    for (int mi = 0; mi < 4; ++mi) {
        int r = e0 + mi * 16 + cl; if (r > n - 1) r = n - 1;
        arow[mi] = emb + (size_t)r * HID + q * 8;
    }
    // B base for this lane: group (tb*4+c)*8/... grp = ((tb*4+c)*2+ks)*4+q
    const ushort* bb = Wt4 + ((size_t)q * HID + wave * 64 + cl) * 8;

    f32x4 acc[4][4] = {};

    #pragma unroll
    for (int c = 0; c < 4; ++c) {
        // ---- B first (oldest in vmem queue) ----
        bf16x8 bfr[2][4];
        #pragma unroll
        for (int ks = 0; ks < 2; ++ks)
            #pragma unroll
            for (int ni = 0; ni < 4; ++ni)
                bfr[ks][ni] = *reinterpret_cast<const bf16x8*>(
                    bb + (((size_t)((tb * 4 + c) * 2 + ks) * 4) * HID + ni * 16) * 8);
        // ---- A loads (newer; stay in flight across the B wait) ----
        float4 a0[2][4], a1[2][4];
        #pragma unroll
        for (int ks = 0; ks < 2; ++ks)
            #pragma unroll
            for (int mi = 0; mi < 4; ++mi) {
                const float* p = arow[mi] + c * 64 + ks * 32;
                a0[ks][mi] = *reinterpret_cast<const float4*>(p);
                a1[ks][mi] = *reinterpret_cast<const float4*>(p + 4);
            }
        // ---- pack + MFMA ----
        #pragma unroll
        for (int ks = 0; ks < 2; ++ks)
            #pragma unroll
            for (int mi = 0; mi < 4; ++mi) {
                union { uint32_t d[4]; bf16x8 v; } af;
                af.d[0] = pack2bf(a0[ks][mi].x, a0[ks][mi].y);
                af.d[1] = pack2bf(a0[ks][mi].z, a0[ks][mi].w);
                af.d[2] = pack2bf(a1[ks][mi].x, a1[ks][mi].y);
                af.d[3] = pack2bf(a1[ks][mi].z, a1[ks][mi].w);
                #pragma unroll
                for (int ni = 0; ni < 4; ++ni)
                    acc[mi][ni] = __builtin_amdgcn_mfma_f32_16x16x32_bf16(
                        af.v, bfr[ks][ni], acc[mi][ni], 0, 0, 0);
            }
    }

    // ---- epilogue: coalesce bf16 C through LDS (single barrier) ----
    #pragma unroll
    for (int mi = 0; mi < 4; ++mi)
        #pragma unroll
        for (int ni = 0; ni < 4; ++ni)
            #pragma unroll
            for (int r = 0; r < 4; ++r)
                Cs[(mi * 16 + q * 4 + r) * LDC + wave * 64 + ni * 16 + cl] =
                    f2bf(acc[mi][ni][r]);
    __syncthreads();

    const int srow = t >> 2, scol = (t & 3) * 64;
    if (e0 + srow < n) {
        ushort* dst = uo + (size_t)(e0 + srow) * HID + scol;
        #pragma unroll
        for (int i = 0; i < 8; ++i) {
            uint4 w = *reinterpret_cast<const uint4*>(&Cs[srow * LDC + scol + i * 8]);
            *reinterpret_cast<uint4*>(dst + i * 8) = w;
        }
    }
}

// -------- phase 2: per-edge  logit = relu(u[s]+v[d]+b1) . W2 + b2 --------
__global__ __launch_bounds__(256, 8)
void lp_edge(const ushort* __restrict__ u, const ushort* __restrict__ v,
             const int* __restrict__ eli,
             const float* __restrict__ b1, const float* __restrict__ W2,
             const float* __restrict__ b2, float* __restrict__ out,
             int E, int nwaves) {
    const int lane = threadIdx.x & 63;
    const int half = lane >> 5, sub = lane & 31;
    const int wid  = blockIdx.x * (blockDim.x >> 6) + (threadIdx.x >> 6);

    float b1v[8], w2v[8];
    {
        const float4* p1 = reinterpret_cast<const float4*>(b1 + sub * 8);
        const float4* p2 = reinterpret_cast<const float4*>(W2 + sub * 8);
        float4 a = p1[0], b = p1[1], c = p2[0], d = p2[1];
        b1v[0]=a.x; b1v[1]=a.y; b1v[2]=a.z; b1v[3]=a.w;
        b1v[4]=b.x; b1v[5]=b.y; b1v[6]=b.z; b1v[7]=b.w;
        w2v[0]=c.x; w2v[1]=c.y; w2v[2]=c.z; w2v[3]=c.w;
        w2v[4]=d.x; w2v[5]=d.y; w2v[6]=d.z; w2v[7]=d.w;
    }
    const float bias2 = b2[0];
    const ushort* tab  = half ? v : u;
    const int*    idxp = eli + (size_t)half * E;

    for (int base = wid * 8; base < E; base += nwaves * 8) {
        uint4 g[8];
        #pragma unroll
        for (int j = 0; j < 8; ++j) {
            int e = base + j; if (e > E - 1) e = E - 1;
            int row = idxp[e];
            g[j] = *reinterpret_cast<const uint4*>(tab + (size_t)row * HID + sub * 8);
        }
        float res = 0.f;
        #pragma unroll
        for (int j = 0; j < 8; ++j) {
            uint32_t pd[4], gd[4] = { g[j].x, g[j].y, g[j].z, g[j].w };
            #pragma unroll
            for (int c = 0; c < 4; ++c) pd[c] = (uint32_t)__shfl_xor((int)gd[c], 32);
            float acc = 0.f;
            #pragma unroll
            for (int c = 0; c < 4; ++c) {
                float a0 = uaf(gd[c] << 16), a1 = uaf(gd[c] & 0xffff0000u);
                float o0 = uaf(pd[c] << 16), o1 = uaf(pd[c] & 0xffff0000u);
                float h0 = fmaxf(a0 + o0 + b1v[2 * c], 0.f);
                float h1 = fmaxf(a1 + o1 + b1v[2 * c + 1], 0.f);
                acc = fmaf(h0, w2v[2 * c], acc);
                acc = fmaf(h1, w2v[2 * c + 1], acc);
            }
            #pragma unroll
            for (int m = 1; m <= 16; m <<= 1) acc += __shfl_xor(acc, m);
            if (half == 0 && sub == j) res = acc + bias2;
        }
        int e = base + sub;
        if (half == 0 && sub < 8 && e < E) out[e] = res;
    }
}

// -------- fallback (monolithic) if ws is too small --------
__global__ __launch_bounds__(256, 3)
void lp_mono(const float* __restrict__ es, const float* __restrict__ ed,
             const int* __restrict__ eli, const float* __restrict__ W1,
             const float* __restrict__ b1, const float* __restrict__ W2,
             const float* __restrict__ b2,
             float* __restrict__ out, int E) {
    __shared__ __align__(16) ushort As[2][BM * LDA];
    __shared__ int   sIdx[2][BM];
    __shared__ float hred[4][BM];

    const int t = threadIdx.x, e0 = blockIdx.x * BM;
    const int wave = t >> 6, lane = t & 63, q = lane >> 4, cl = lane & 15;

    if (t < 2 * BM) {
        int which = t >> 6, e = t & 63;
        int ge = e0 + e; if (ge > E - 1) ge = E - 1;
        sIdx[which][e] = eli[which * E + ge];
    }
    __syncthreads();

    int ge_[2], go_[2], rsrc[2], rdst[2];
    #pragma unroll
    for (int i = 0; i < 2; ++i) {
        int c2 = t + 256 * i;
        ge_[i] = c2 >> 3; go_[i] = c2 & 7;
        rsrc[i] = sIdx[0][ge_[i]];
        rdst[i] = sIdx[1][ge_[i]];
    }
    float4 g0[2], g1[2];
    auto gather = [&](int c) {
        const float* tab = (c < 4) ? es : ed;
        #pragma unroll
        for (int i = 0; i < 2; ++i) {
            int row = (c < 4) ? rsrc[i] : rdst[i];
            const float* p = tab + (size_t)row * HID + (c & 3) * 64 + go_[i] * 8;
            g0[i] = *reinterpret_cast<const float4*>(p);
            g1[i] = *reinterpret_cast<const float4*>(p + 4);
        }
    };
    auto cvstore = [&](int buf) {
        #pragma unroll
        for (int i = 0; i < 2; ++i) {
            uint4 v;
            v.x = pack2bf(g0[i].x, g0[i].y); v.y = pack2bf(g0[i].z, g0[i].w);
            v.z = pack2bf(g1[i].x, g1[i].y); v.w = pack2bf(g1[i].z, g1[i].w);
            *reinterpret_cast<uint4*>(&As[buf][ge_[i] * LDA + go_[i] * 8]) = v;
        }
    };
    gather(0); cvstore(0); __syncthreads();
    f32x4 acc[4][4] = {};
    #pragma unroll
    for (int c = 0; c < 8; ++c) {
        const int cur = c & 1;
        if (c < 7) gather(c + 1);
        #pragma unroll
        for (int ks = 0; ks < 2; ++ks) {
            bf16x8 af[4], bfr[4];
            #pragma unroll
            for (int mi = 0; mi < 4; ++mi)
                af[mi] = *reinterpret_cast<const bf16x8*>(
                    &As[cur][(mi * 16 + cl) * LDA + ks * 32 + q * 8]);
            #pragma unroll
            for (int ni = 0; ni < 4; ++ni) {
                int nn = wave * 64 + ni * 16 + cl;
                union { ushort s[8]; bf16x8 v; } u;
                #pragma unroll
                for (int j = 0; j < 8; ++j)
                    u.s[j] = f2bf(W1[(size_t)(c * 64 + ks * 32 + q * 8 + j) * HID + nn]);
                bfr[ni] = u.v;
            }
            #pragma unroll
            for (int mi = 0; mi < 4; ++mi)
                #pragma unroll
                for (int ni = 0; ni < 4; ++ni)
                    acc[mi][ni] = __builtin_amdgcn_mfma_f32_16x16x32_bf16(
                        af[mi], bfr[ni], acc[mi][ni], 0, 0, 0);
        }
        if (c < 7) { cvstore(cur ^ 1); __syncthreads(); }
    }
    float b1v[4], w2v[4];
    #pragma unroll
    for (int ni = 0; ni < 4; ++ni) {
        int col = wave * 64 + ni * 16 + cl;
        b1v[ni] = b1[col]; w2v[ni] = W2[col];
    }
    #pragma unroll
    for (int mi = 0; mi < 4; ++mi) {
        #pragma unroll
        for (int r = 0; r < 4; ++r) {
            float s = 0.f;
            #pragma unroll
            for (int ni = 0; ni < 4; ++ni) {
                float h = acc[mi][ni][r] + b1v[ni];
                h = fmaxf(h, 0.f);
                s += h * w2v[ni];
            }
            s += __shfl_xor(s, 1); s += __shfl_xor(s, 2);
            s += __shfl_xor(s, 4); s += __shfl_xor(s, 8);
            if (cl == 0) hred[wave][mi * 16 + q * 4 + r] = s;
        }
    }
    __syncthreads();
    if (t < BM) {
        int ge = e0 + t;
        if (ge < E)
            out[ge] = hred[0][t] + hred[1][t] + hred[2][t] + hred[3][t] + b2[0];
    }
}

extern "C" void kernel_launch(void* const* d_in, const int* in_sizes, int n_in,
                              void* d_out, int out_size, void* d_ws, size_t ws_size,
                              hipStream_t stream) {
    const float* emb_src = (const float*)d_in[0];
    const float* emb_dst = (const float*)d_in[1];
    const int*   eli     = (const int*)d_in[2];
    const float* W1      = (const float*)d_in[3];
    const float* b1      = (const float*)d_in[4];
    const float* W2      = (const float*)d_in[5];
    const float* b2      = (const float*)d_in[6];
    float*       out     = (float*)d_out;

    const int E   = in_sizes[2] / 2;
    const int n0n = in_sizes[0] / HID;
    const int n1n = in_sizes[1] / HID;

    const size_t wtB = (size_t)2 * HID * 2 * HID * sizeof(ushort);   // 256 KB (Wt4: 512x256)
    const size_t uB  = (size_t)n0n * HID * sizeof(ushort);
    const size_t vB  = (size_t)n1n * HID * sizeof(ushort);

    ushort* Wt4 = (ushort*)d_ws;
    ushort* u0  = (ushort*)((char*)d_ws + wtB);
    ushort* u1  = (ushort*)((char*)d_ws + wtB + uB);

    const int fullPath = ws_size >= wtB + uB + vB;

    if (fullPath) {
        conv_w1<<<128, 256, 0, stream>>>(W1, Wt4);
        const int nb0 = (n0n + BM - 1) / BM;
        const int nb1 = (n1n + BM - 1) / BM;
        node_gemm<<<nb0 + nb1, 256, 0, stream>>>(emb_src, emb_dst, Wt4,
                                                 u0, u1, n0n, n1n, nb0);
        const int eb = 2048;
        lp_edge<<<eb, 256, 0, stream>>>(u0, u1, eli, b1, W2, b2, out, E, eb * 4);
    } else {
        const int nb = (E + BM - 1) / BM;
        lp_mono<<<nb, 256, 0, stream>>>(emb_src, emb_dst, eli, W1,
                                        b1, W2, b2, out, E);
    }
}

// Round 7
// 322.539 us; speedup vs baseline: 1.2180x; 1.2180x over previous
//
#include <hip/hip_runtime.h>
#include <hip/hip_bf16.h>
#include <stdint.h>

#define HID 256
#define BM  64
#define LDA 68    // As row stride in ushorts (34 dwords == 2 mod 32: measured zero-conflict)
#define LDC 264   // Cs row stride in ushorts

typedef __bf16 bf16x8 __attribute__((ext_vector_type(8)));
typedef float  f32x4  __attribute__((ext_vector_type(4)));

__device__ __forceinline__ ushort f2bf(float x) {
    union { float f; uint32_t u; } v; v.f = x;
    uint32_t u = v.u;
    uint32_t r = u + 0x7fffu + ((u >> 16) & 1u);   // RNE
    return (ushort)(r >> 16);
}

__device__ __forceinline__ uint32_t pack2bf(float a, float b) {
    union { float f; uint32_t u; } ua, ub;
    ua.f = a; ub.f = b;
    return __builtin_amdgcn_perm(ub.u + 0x8000u, ua.u + 0x8000u, 0x07060302u);
}

__device__ __forceinline__ float uaf(uint32_t x) {
    union { uint32_t u; float f; } c; c.u = x; return c.f;
}

// W1[512][256] fp32 -> Wt4 bf16, layout [grp = k/8][n 0..255][j = k%8]
// B-fragment loads are then 16B/lane contiguous (256-B runs per quad).
__global__ void conv_w1(const float* __restrict__ W1, ushort* __restrict__ Wt4) {
    __shared__ ushort tr[32][33];
    const int bk = blockIdx.x >> 3;   // k-tile 0..15
    const int bn = blockIdx.x & 7;    // n-tile 0..7
    const int t  = threadIdx.x;
    #pragma unroll
    for (int i = 0; i < 4; ++i) {
        int e = t + 256 * i; int r = e >> 5, cc = e & 31;
        tr[cc][r] = f2bf(W1[(size_t)(bk * 32 + r) * HID + bn * 32 + cc]);
    }
    __syncthreads();
    #pragma unroll
    for (int i = 0; i < 4; ++i) {
        int e = t + 256 * i; int rn = e >> 5, ck = e & 31;
        int k = bk * 32 + ck;
        int grp = k >> 3;
        int j   = k & 7;
        int n   = bn * 32 + rn;
        Wt4[((size_t)grp * HID + n) * 8 + j] = tr[rn][ck];
    }
}

// -------- phase 1: dense per-node GEMM  u = emb @ W1half  (bf16 out) --------
// All global loads/stores are lane-contiguous (16 B/lane adjacent). B loads are
// issued before the A prefetch each interval so the MFMA's in-order vmcnt wait
// on B leaves the A prefetch in flight.
__global__ __launch_bounds__(256, 3)
void node_gemm(const float* __restrict__ emb0, const float* __restrict__ emb1,
               const ushort* __restrict__ Wt4,
               ushort* __restrict__ u0, ushort* __restrict__ u1,
               int n0, int n1, int nb0) {
    __shared__ __align__(16) union {
        ushort As[2][BM * LDA];   // 17408 B (K-loop)
        ushort Cs[BM * LDC];      // 33792 B (epilogue)
    } sm;

    const int t    = threadIdx.x;
    const int tb   = (blockIdx.x >= nb0) ? 1 : 0;
    const int bloc = blockIdx.x - tb * nb0;
    const float*  emb = tb ? emb1 : emb0;
    ushort*       uo  = tb ? u1 : u0;
    const int     n   = tb ? n1 : n0;
    const int     e0  = bloc * BM;

    const int wave = t >> 6, lane = t & 63, q = lane >> 4, cl = lane & 15;

    // staging: f = t + 256*i -> row = (t>>4)+16*i, seg = t&15 (16B unit)
    const int r0  = t >> 4, seg = t & 15;
    int rcl[4];
    #pragma unroll
    for (int i = 0; i < 4; ++i) {
        int r = e0 + r0 + 16 * i; if (r > n - 1) r = n - 1;
        rcl[i] = r;
    }
    const float* abase = emb + seg * 4;
    const int    sbase = r0 * LDA + seg * 4;

    float4 g[4];
    auto gather = [&](int c) {
        #pragma unroll
        for (int i = 0; i < 4; ++i)
            g[i] = *reinterpret_cast<const float4*>(abase + (size_t)rcl[i] * HID + c * 64);
    };
    auto cvstore = [&](int buf) {
        #pragma unroll
        for (int i = 0; i < 4; ++i) {
            uint2 v;
            v.x = pack2bf(g[i].x, g[i].y);
            v.y = pack2bf(g[i].z, g[i].w);
            *reinterpret_cast<uint2*>(&sm.As[buf][sbase + i * 16 * LDA]) = v;
        }
    };

    gather(0); cvstore(0);
    __syncthreads();

    f32x4 acc[4][4] = {};

    #pragma unroll
    for (int c = 0; c < 4; ++c) {
        const int cur = c & 1;
        // ---- B loads first (oldest in vmem queue): grp = tb*32 + c*8 + ks*4 + q
        bf16x8 bfr[2][4];
        #pragma unroll
        for (int ks = 0; ks < 2; ++ks) {
            const ushort* bb = Wt4 + ((size_t)(tb * 32 + c * 8 + ks * 4 + q) * HID) * 8;
            #pragma unroll
            for (int ni = 0; ni < 4; ++ni)
                bfr[ks][ni] = *reinterpret_cast<const bf16x8*>(
                    bb + (wave * 64 + ni * 16 + cl) * 8);
        }
        // ---- A prefetch (newer: stays in flight across the MFMA block)
        if (c < 3) gather(c + 1);
        // ---- MFMA
        #pragma unroll
        for (int ks = 0; ks < 2; ++ks) {
            bf16x8 af[4];
            #pragma unroll
            for (int mi = 0; mi < 4; ++mi)
                af[mi] = *reinterpret_cast<const bf16x8*>(
                    &sm.As[cur][(mi * 16 + cl) * LDA + ks * 32 + q * 8]);
            #pragma unroll
            for (int mi = 0; mi < 4; ++mi)
                #pragma unroll
                for (int ni = 0; ni < 4; ++ni)
                    acc[mi][ni] = __builtin_amdgcn_mfma_f32_16x16x32_bf16(
                        af[mi], bfr[ks][ni], acc[mi][ni], 0, 0, 0);
        }
        if (c < 3) { cvstore(cur ^ 1); __syncthreads(); }
    }

    __syncthreads();   // all As reads done before Cs overwrites the union
    #pragma unroll
    for (int mi = 0; mi < 4; ++mi)
        #pragma unroll
        for (int ni = 0; ni < 4; ++ni)
            #pragma unroll
            for (int r = 0; r < 4; ++r)
                sm.Cs[(mi * 16 + q * 4 + r) * LDC + wave * 64 + ni * 16 + cl] =
                    f2bf(acc[mi][ni][r]);
    __syncthreads();

    // coalesced store: f = t + 256*i -> row = f>>5, 16B-unit = f&31 (512-B runs)
    #pragma unroll
    for (int i = 0; i < 8; ++i) {
        int f = t + 256 * i;
        int row = f >> 5, unit = f & 31;
        if (e0 + row < n) {
            uint4 w = *reinterpret_cast<const uint4*>(&sm.Cs[row * LDC + unit * 8]);
            *reinterpret_cast<uint4*>(uo + (size_t)(e0 + row) * HID + unit * 8) = w;
        }
    }
}

// -------- phase 2: per-edge  logit = relu(u[s]+v[d]+b1) . W2 + b2 --------
__global__ __launch_bounds__(256, 4)
void lp_edge(const ushort* __restrict__ u, const ushort* __restrict__ v,
             const int* __restrict__ eli,
             const float* __restrict__ b1, const float* __restrict__ W2,
             const float* __restrict__ b2, float* __restrict__ out,
             int E, int nwaves) {
    const int lane = threadIdx.x & 63;
    const int half = lane >> 5, sub = lane & 31;
    const int wid  = blockIdx.x * (blockDim.x >> 6) + (threadIdx.x >> 6);

    float b1v[8], w2v[8];
    {
        const float4* p1 = reinterpret_cast<const float4*>(b1 + sub * 8);
        const float4* p2 = reinterpret_cast<const float4*>(W2 + sub * 8);
        float4 a = p1[0], b = p1[1], c = p2[0], d = p2[1];
        b1v[0]=a.x; b1v[1]=a.y; b1v[2]=a.z; b1v[3]=a.w;
        b1v[4]=b.x; b1v[5]=b.y; b1v[6]=b.z; b1v[7]=b.w;
        w2v[0]=c.x; w2v[1]=c.y; w2v[2]=c.z; w2v[3]=c.w;
        w2v[4]=d.x; w2v[5]=d.y; w2v[6]=d.z; w2v[7]=d.w;
    }
    const float bias2 = b2[0];
    const ushort* tab  = half ? v : u;
    const int*    idxp = eli + (size_t)half * E;

    for (int base = wid * 8; base < E; base += nwaves * 8) {
        uint4 g[8];
        #pragma unroll
        for (int j = 0; j < 8; ++j) {
            int e = base + j; if (e > E - 1) e = E - 1;
            int row = idxp[e];
            g[j] = *reinterpret_cast<const uint4*>(tab + (size_t)row * HID + sub * 8);
        }
        float res = 0.f;
        #pragma unroll
        for (int j = 0; j < 8; ++j) {
            uint32_t pd[4], gd[4] = { g[j].x, g[j].y, g[j].z, g[j].w };
            #pragma unroll
            for (int c = 0; c < 4; ++c) pd[c] = (uint32_t)__shfl_xor((int)gd[c], 32);
            float acc = 0.f;
            #pragma unroll
            for (int c = 0; c < 4; ++c) {
                float a0 = uaf(gd[c] << 16), a1 = uaf(gd[c] & 0xffff0000u);
                float o0 = uaf(pd[c] << 16), o1 = uaf(pd[c] & 0xffff0000u);
                float h0 = fmaxf(a0 + o0 + b1v[2 * c], 0.f);
                float h1 = fmaxf(a1 + o1 + b1v[2 * c + 1], 0.f);
                acc = fmaf(h0, w2v[2 * c], acc);
                acc = fmaf(h1, w2v[2 * c + 1], acc);
            }
            #pragma unroll
            for (int m = 1; m <= 16; m <<= 1) acc += __shfl_xor(acc, m);
            if (half == 0 && sub == j) res = acc + bias2;
        }
        int e = base + sub;
        if (half == 0 && sub < 8 && e < E) out[e] = res;
    }
}

// -------- fallback (monolithic) if ws is too small --------
__global__ __launch_bounds__(256, 3)
void lp_mono(const float* __restrict__ es, const float* __restrict__ ed,
             const int* __restrict__ eli, const float* __restrict__ W1,
             const float* __restrict__ b1, const float* __restrict__ W2,
             const float* __restrict__ b2,
             float* __restrict__ out, int E) {
    __shared__ __align__(16) ushort As[2][BM * LDA];
    __shared__ int   sIdx[2][BM];
    __shared__ float hred[4][BM];

    const int t = threadIdx.x, e0 = blockIdx.x * BM;
    const int wave = t >> 6, lane = t & 63, q = lane >> 4, cl = lane & 15;

    if (t < 2 * BM) {
        int which = t >> 6, e = t & 63;
        int ge = e0 + e; if (ge > E - 1) ge = E - 1;
        sIdx[which][e] = eli[which * E + ge];
    }
    __syncthreads();

    int ge_[2], go_[2], rsrc[2], rdst[2];
    #pragma unroll
    for (int i = 0; i < 2; ++i) {
        int c2 = t + 256 * i;
        ge_[i] = c2 >> 3; go_[i] = c2 & 7;
        rsrc[i] = sIdx[0][ge_[i]];
        rdst[i] = sIdx[1][ge_[i]];
    }
    float4 g0[2], g1[2];
    auto gather = [&](int c) {
        const float* tab = (c < 4) ? es : ed;
        #pragma unroll
        for (int i = 0; i < 2; ++i) {
            int row = (c < 4) ? rsrc[i] : rdst[i];
            const float* p = tab + (size_t)row * HID + (c & 3) * 64 + go_[i] * 8;
            g0[i] = *reinterpret_cast<const float4*>(p);
            g1[i] = *reinterpret_cast<const float4*>(p + 4);
        }
    };
    auto cvstore = [&](int buf) {
        #pragma unroll
        for (int i = 0; i < 2; ++i) {
            uint4 v;
            v.x = pack2bf(g0[i].x, g0[i].y); v.y = pack2bf(g0[i].z, g0[i].w);
            v.z = pack2bf(g1[i].x, g1[i].y); v.w = pack2bf(g1[i].z, g1[i].w);
            *reinterpret_cast<uint4*>(&As[buf][ge_[i] * LDA + go_[i] * 8]) = v;
        }
    };
    gather(0); cvstore(0); __syncthreads();
    f32x4 acc[4][4] = {};
    #pragma unroll
    for (int c = 0; c < 8; ++c) {
        const int cur = c & 1;
        if (c < 7) gather(c + 1);
        #pragma unroll
        for (int ks = 0; ks < 2; ++ks) {
            bf16x8 af[4], bfr[4];
            #pragma unroll
            for (int mi = 0; mi < 4; ++mi)
                af[mi] = *reinterpret_cast<const bf16x8*>(
                    &As[cur][(mi * 16 + cl) * LDA + ks * 32 + q * 8]);
            #pragma unroll
            for (int ni = 0; ni < 4; ++ni) {
                int nn = wave * 64 + ni * 16 + cl;
                union { ushort s[8]; bf16x8 v; } u;
                #pragma unroll
                for (int j = 0; j < 8; ++j)
                    u.s[j] = f2bf(W1[(size_t)(c * 64 + ks * 32 + q * 8 + j) * HID + nn]);
                bfr[ni] = u.v;
            }
            #pragma unroll
            for (int mi = 0; mi < 4; ++mi)
                #pragma unroll
                for (int ni = 0; ni < 4; ++ni)
                    acc[mi][ni] = __builtin_amdgcn_mfma_f32_16x16x32_bf16(
                        af[mi], bfr[ni], acc[mi][ni], 0, 0, 0);
        }
        if (c < 7) { cvstore(cur ^ 1); __syncthreads(); }
    }
    float b1v[4], w2v[4];
    #pragma unroll
    for (int ni = 0; ni < 4; ++ni) {
        int col = wave * 64 + ni * 16 + cl;
        b1v[ni] = b1[col]; w2v[ni] = W2[col];
    }
    #pragma unroll
    for (int mi = 0; mi < 4; ++mi) {
        #pragma unroll
        for (int r = 0; r < 4; ++r) {
            float s = 0.f;
            #pragma unroll
            for (int ni = 0; ni < 4; ++ni) {
                float h = acc[mi][ni][r] + b1v[ni];
                h = fmaxf(h, 0.f);
                s += h * w2v[ni];
            }
            s += __shfl_xor(s, 1); s += __shfl_xor(s, 2);
            s += __shfl_xor(s, 4); s += __shfl_xor(s, 8);
            if (cl == 0) hred[wave][mi * 16 + q * 4 + r] = s;
        }
    }
    __syncthreads();
    if (t < BM) {
        int ge = e0 + t;
        if (ge < E)
            out[ge] = hred[0][t] + hred[1][t] + hred[2][t] + hred[3][t] + b2[0];
    }
}

extern "C" void kernel_launch(void* const* d_in, const int* in_sizes, int n_in,
                              void* d_out, int out_size, void* d_ws, size_t ws_size,
                              hipStream_t stream) {
    const float* emb_src = (const float*)d_in[0];
    const float* emb_dst = (const float*)d_in[1];
    const int*   eli     = (const int*)d_in[2];
    const float* W1      = (const float*)d_in[3];
    const float* b1      = (const float*)d_in[4];
    const float* W2      = (const float*)d_in[5];
    const float* b2      = (const float*)d_in[6];
    float*       out     = (float*)d_out;

    const int E   = in_sizes[2] / 2;
    const int n0n = in_sizes[0] / HID;
    const int n1n = in_sizes[1] / HID;

    const size_t wtB = (size_t)2 * HID * 2 * HID * sizeof(ushort);   // 256 KB
    const size_t uB  = (size_t)n0n * HID * sizeof(ushort);
    const size_t vB  = (size_t)n1n * HID * sizeof(ushort);

    ushort* Wt4 = (ushort*)d_ws;
    ushort* u0  = (ushort*)((char*)d_ws + wtB);
    ushort* u1  = (ushort*)((char*)d_ws + wtB + uB);

    const int fullPath = ws_size >= wtB + uB + vB;

    if (fullPath) {
        conv_w1<<<128, 256, 0, stream>>>(W1, Wt4);
        const int nb0 = (n0n + BM - 1) / BM;
        const int nb1 = (n1n + BM - 1) / BM;
        node_gemm<<<nb0 + nb1, 256, 0, stream>>>(emb_src, emb_dst, Wt4,
                                                 u0, u1, n0n, n1n, nb0);
        const int eb = 1024;
        lp_edge<<<eb, 256, 0, stream>>>(u0, u1, eli, b1, W2, b2, out, E, eb * 4);
    } else {
        const int nb = (E + BM - 1) / BM;
        lp_mono<<<nb, 256, 0, stream>>>(emb_src, emb_dst, eli, W1,
                                        b1, W2, b2, out, E);
    }
}